// Round 1
// baseline (242.031 us; speedup 1.0000x reference)
//
#include <hip/hip_runtime.h>
#include <float.h>

#define B_  8
#define C_  16
#define N_  (B_*C_)
#define F_  256
#define H_  112
#define W_  112
#define NB_ 3

// ws layout per cell (16 ints): y0,y1,x0,x1, ys[3], ye[3], xs[3], xe[3]

__global__ void bbox_kernel(const int* __restrict__ mask, int* __restrict__ bb) {
    int n = blockIdx.x;
    __shared__ int rowsAny[H_];
    __shared__ int colsAny[W_];
    int t = threadIdx.x;
    if (t < H_) { rowsAny[t] = 0; colsAny[t] = 0; }
    __syncthreads();
    if (t < H_) {
        const int* mrow = mask + (size_t)n * H_ * W_ + (size_t)t * W_;
        int any = 0;
        for (int x = 0; x < W_; ++x) {
            if (mrow[x]) { any = 1; colsAny[x] = 1; }   // benign write race
        }
        rowsAny[t] = any;
    }
    __syncthreads();
    if (t == 0) {
        int y0 = 0;  while (y0 < H_ && !rowsAny[y0]) ++y0;
        int y1 = H_; while (y1 > y0 && !rowsAny[y1-1]) --y1;
        int x0 = 0;  while (x0 < W_ && !colsAny[x0]) ++x0;
        int x1 = W_; while (x1 > x0 && !colsAny[x1-1]) --x1;
        int* o = bb + n * 16;
        o[0] = y0; o[1] = y1; o[2] = x0; o[3] = x1;
        int szy = y1 - y0, szx = x1 - x0;
        for (int i = 0; i < NB_; ++i) {
            o[4  + i] = y0 + (i * szy) / NB_;
            o[7  + i] = y0 + ((i + 1) * szy + NB_ - 1) / NB_;
            o[10 + i] = x0 + (i * szx) / NB_;
            o[13 + i] = x0 + ((i + 1) * szx + NB_ - 1) / NB_;
        }
    }
}

// grid: (N_, F_/4); block: 256 threads = 4 waves, one feature per wave.
__global__ __launch_bounds__(256) void pool_kernel(
        const float* __restrict__ feat, const int* __restrict__ mask,
        const int* __restrict__ bb, float* __restrict__ out) {
    int n = blockIdx.x;
    int b = n / C_;
    const int* o = bb + n * 16;
    int y0 = o[0], y1 = o[1], x0 = o[2], x1 = o[3];
    int bh = y1 - y0, bw = x1 - x0;          // each <= 35

    __shared__ float lmask[36 * 36];
    int tot = bh * bw;
    const int* mbase = mask + (size_t)n * H_ * W_;
    for (int idx = threadIdx.x; idx < tot; idx += 256) {
        int dy = idx / bw, dx = idx - dy * bw;
        lmask[idx] = mbase[(size_t)(y0 + dy) * W_ + (x0 + dx)] ? 1.0f : 0.0f;
    }
    __syncthreads();

    int wave = threadIdx.x >> 6;
    int lane = threadIdx.x & 63;
    int f = blockIdx.y * 4 + wave;
    const float* fbase = feat + (size_t)(b * F_ + f) * H_ * W_;
    int x = x0 + lane;
    bool act = lane < bw;

    int ys0 = o[4], ys1 = o[5], ys2 = o[6];
    int ye0 = o[7], ye1 = o[8], ye2 = o[9];

    float acc0 = -FLT_MAX, acc1 = -FLT_MAX, acc2 = -FLT_MAX;
    for (int dy = 0; dy < bh; ++dy) {
        int y = y0 + dy;
        float v = -FLT_MAX;
        if (act) v = lmask[dy * bw + lane] * fbase[(size_t)y * W_ + x];
        // bins may overlap by one row -> test all three ranges
        if (y >= ys0 && y < ye0) acc0 = fmaxf(acc0, v);
        if (y >= ys1 && y < ye1) acc1 = fmaxf(acc1, v);
        if (y >= ys2 && y < ye2) acc2 = fmaxf(acc2, v);
    }

    float accs[3] = {acc0, acc1, acc2};
    float* op = out + ((size_t)n * F_ + f) * (NB_ * NB_);
    #pragma unroll
    for (int i = 0; i < NB_; ++i) {
        #pragma unroll
        for (int j = 0; j < NB_; ++j) {
            int xs = o[10 + j], xe = o[13 + j];
            float val = (act && x >= xs && x < xe) ? accs[i] : -FLT_MAX;
            #pragma unroll
            for (int off = 32; off > 0; off >>= 1)
                val = fmaxf(val, __shfl_xor(val, off));
            if (lane == 0) op[i * NB_ + j] = val;
        }
    }
}

extern "C" void kernel_launch(void* const* d_in, const int* in_sizes, int n_in,
                              void* d_out, int out_size, void* d_ws, size_t ws_size,
                              hipStream_t stream) {
    const float* feat = (const float*)d_in[0];
    const int*   mask = (const int*)d_in[1];
    // d_in[2] (cell_counts) is unused by the reference computation.
    int* bb = (int*)d_ws;

    bbox_kernel<<<N_, 128, 0, stream>>>(mask, bb);
    dim3 grid(N_, F_ / 4);
    pool_kernel<<<grid, 256, 0, stream>>>(feat, mask, bb, (float*)d_out);
}

// Round 2
// 197.396 us; speedup vs baseline: 1.2261x; 1.2261x over previous
//
#include <hip/hip_runtime.h>
#include <float.h>

#define B_  8
#define C_  16
#define N_  (B_*C_)
#define F_  256
#define H_  112
#define W_  112
#define HW_ (H_*W_)
#define NB_ 3
#define FPW 4          // features per wave
#define WPB 4          // waves per block
#define FPB (FPW*WPB)  // features per block

// ws layout per cell (16 ints): y0,y1,x0,x1, ys[3], ye[3], xs[3], xe[3]

__global__ __launch_bounds__(256) void bbox_kernel(const int* __restrict__ mask,
                                                   int* __restrict__ bb) {
    int n = blockIdx.x;
    int t = threadIdx.x;
    __shared__ int rowsAny[H_];
    __shared__ int colsAny[W_];
    __shared__ int smin[256];
    __shared__ int smax[256];
    if (t < H_) rowsAny[t] = 0;
    if (t < W_) colsAny[t] = 0;
    __syncthreads();
    const int* m = mask + (size_t)n * HW_;
    // coalesced scan; benign-race flag stores
    for (int idx = t; idx < HW_; idx += 256) {
        if (m[idx]) {
            int y = idx / W_;
            int x = idx - y * W_;
            rowsAny[y] = 1;
            colsAny[x] = 1;
        }
    }
    __syncthreads();
    smin[t] = (t < H_ && rowsAny[t]) ? t : 0x3fffffff;
    smax[t] = (t < H_ && rowsAny[t]) ? t : -1;
    __syncthreads();
    #pragma unroll
    for (int s = 128; s > 0; s >>= 1) {
        if (t < s) { smin[t] = min(smin[t], smin[t+s]); smax[t] = max(smax[t], smax[t+s]); }
        __syncthreads();
    }
    int y0 = smin[0], y1 = smax[0] + 1;
    __syncthreads();
    smin[t] = (t < W_ && colsAny[t]) ? t : 0x3fffffff;
    smax[t] = (t < W_ && colsAny[t]) ? t : -1;
    __syncthreads();
    #pragma unroll
    for (int s = 128; s > 0; s >>= 1) {
        if (t < s) { smin[t] = min(smin[t], smin[t+s]); smax[t] = max(smax[t], smax[t+s]); }
        __syncthreads();
    }
    if (t == 0) {
        int x0 = smin[0], x1 = smax[0] + 1;
        int* o = bb + n * 16;
        o[0] = y0; o[1] = y1; o[2] = x0; o[3] = x1;
        int szy = y1 - y0, szx = x1 - x0;
        for (int i = 0; i < NB_; ++i) {
            o[4+i]  = y0 + (i*szy)/NB_;
            o[7+i]  = y0 + ((i+1)*szy + NB_-1)/NB_;
            o[10+i] = x0 + (i*szx)/NB_;
            o[13+i] = x0 + ((i+1)*szx + NB_-1)/NB_;
        }
    }
}

// grid (N_, F_/FPB); block 256 = 4 waves; wave handles FPW consecutive features.
__global__ __launch_bounds__(256) void pool_kernel(
        const float* __restrict__ feat, const int* __restrict__ mask,
        const int* __restrict__ bb, float* __restrict__ out) {
    int n = blockIdx.x;
    int b = n >> 4;                      // / C_
    const int* o = bb + n * 16;
    int y0 = o[0], x0 = o[2];
    int bh = o[1] - y0, bw = o[3] - x0;  // each in [11,37]

    __shared__ float lmask[37 * 37];
    {
        const int* mbase = mask + (size_t)n * HW_ + (size_t)y0 * W_ + x0;
        int tot = bh * bw;
        for (int idx = threadIdx.x; idx < tot; idx += 256) {
            int dy = idx / bw, dx = idx - dy * bw;
            lmask[idx] = mbase[dy * W_ + dx] ? 1.0f : 0.0f;
        }
    }
    __syncthreads();

    int wave = threadIdx.x >> 6, lane = threadIdx.x & 63;
    int laneC = lane < bw ? lane : bw - 1;   // clamp -> loads always in-range
    int f0 = blockIdx.y * FPB + wave * FPW;
    const float* p = feat + (size_t)(b * F_ + f0) * HW_ + (size_t)y0 * W_ + x0 + laneC;

    int ys0 = o[4], ys1 = o[5], ys2 = o[6];
    int ye0 = o[7], ye1 = o[8], ye2 = o[9];

    float acc[3][FPW];
    #pragma unroll
    for (int i = 0; i < 3; ++i)
        #pragma unroll
        for (int k = 0; k < FPW; ++k) acc[i][k] = -FLT_MAX;

    // 1-deep software pipeline: prefetch next row while reducing current.
    float fv[FPW];
    #pragma unroll
    for (int k = 0; k < FPW; ++k) fv[k] = p[k * HW_];

    for (int dy = 0; dy < bh; ++dy) {
        int dyn = (dy + 1 < bh) ? dy + 1 : dy;   // last iter re-reads (L1-hot, no OOB)
        int offn = dyn * W_;
        float nv[FPW];
        #pragma unroll
        for (int k = 0; k < FPW; ++k) nv[k] = p[k * HW_ + offn];

        float mv = lmask[dy * bw + laneC];
        int y = y0 + dy;
        bool in0 = (y >= ys0) & (y < ye0);
        bool in1 = (y >= ys1) & (y < ye1);
        bool in2 = (y >= ys2) & (y < ye2);
        #pragma unroll
        for (int k = 0; k < FPW; ++k) {
            float v = mv * fv[k];
            if (in0) acc[0][k] = fmaxf(acc[0][k], v);
            if (in1) acc[1][k] = fmaxf(acc[1][k], v);
            if (in2) acc[2][k] = fmaxf(acc[2][k], v);
        }
        #pragma unroll
        for (int k = 0; k < FPW; ++k) fv[k] = nv[k];
    }

    // Epilogue: lanes >= bw hold garbage accs, but (x < xe <= x0+bw) masks them.
    int x = x0 + lane;
    int xs[3] = {o[10], o[11], o[12]};
    int xe[3] = {o[13], o[14], o[15]};

    #pragma unroll
    for (int k = 0; k < FPW; ++k) {
        float st = 0.0f;
        #pragma unroll
        for (int i = 0; i < 3; ++i) {
            #pragma unroll
            for (int j = 0; j < 3; ++j) {
                float val = (x >= xs[j] && x < xe[j]) ? acc[i][k] : -FLT_MAX;
                #pragma unroll
                for (int off = 32; off; off >>= 1)
                    val = fmaxf(val, __shfl_xor(val, off));
                st = (lane == i * 3 + j) ? val : st;
            }
        }
        if (lane < 9) out[(size_t)(n * F_ + f0 + k) * 9 + lane] = st;
    }
}

extern "C" void kernel_launch(void* const* d_in, const int* in_sizes, int n_in,
                              void* d_out, int out_size, void* d_ws, size_t ws_size,
                              hipStream_t stream) {
    const float* feat = (const float*)d_in[0];
    const int*   mask = (const int*)d_in[1];
    int* bb = (int*)d_ws;

    bbox_kernel<<<N_, 256, 0, stream>>>(mask, bb);
    dim3 grid(N_, F_ / FPB);
    pool_kernel<<<grid, 256, 0, stream>>>(feat, mask, bb, (float*)d_out);
}

// Round 3
// 190.764 us; speedup vs baseline: 1.2687x; 1.0348x over previous
//
#include <hip/hip_runtime.h>
#include <float.h>

#define B_  8
#define C_  16
#define N_  (B_*C_)
#define F_  256
#define H_  112
#define W_  112
#define HW_ (H_*W_)
#define NB_ 3
#define FPW 4          // features per wave
#define WPB 4          // waves per block
#define FPB (FPW*WPB)  // features per block
#define RT  4          // row-tile: rows loaded concurrently per wave

// ws layout per cell (16 ints): y0,y1,x0,x1, ys[3], ye[3], xs[3], xe[3]

__global__ __launch_bounds__(256) void bbox_kernel(const int* __restrict__ mask,
                                                   int* __restrict__ bb) {
    int n = blockIdx.x;
    int t = threadIdx.x;
    __shared__ int rowsAny[H_];
    __shared__ int colsAny[W_];
    __shared__ int smin[256];
    __shared__ int smax[256];
    if (t < H_) rowsAny[t] = 0;
    if (t < W_) colsAny[t] = 0;
    __syncthreads();
    const int* m = mask + (size_t)n * HW_;
    for (int idx = t; idx < HW_; idx += 256) {
        if (m[idx]) {
            int y = idx / W_;
            int x = idx - y * W_;
            rowsAny[y] = 1;   // benign race
            colsAny[x] = 1;
        }
    }
    __syncthreads();
    smin[t] = (t < H_ && rowsAny[t]) ? t : 0x3fffffff;
    smax[t] = (t < H_ && rowsAny[t]) ? t : -1;
    __syncthreads();
    #pragma unroll
    for (int s = 128; s > 0; s >>= 1) {
        if (t < s) { smin[t] = min(smin[t], smin[t+s]); smax[t] = max(smax[t], smax[t+s]); }
        __syncthreads();
    }
    int y0 = smin[0], y1 = smax[0] + 1;
    __syncthreads();
    smin[t] = (t < W_ && colsAny[t]) ? t : 0x3fffffff;
    smax[t] = (t < W_ && colsAny[t]) ? t : -1;
    __syncthreads();
    #pragma unroll
    for (int s = 128; s > 0; s >>= 1) {
        if (t < s) { smin[t] = min(smin[t], smin[t+s]); smax[t] = max(smax[t], smax[t+s]); }
        __syncthreads();
    }
    if (t == 0) {
        int x0 = smin[0], x1 = smax[0] + 1;
        int* o = bb + n * 16;
        o[0] = y0; o[1] = y1; o[2] = x0; o[3] = x1;
        int szy = y1 - y0, szx = x1 - x0;
        for (int i = 0; i < NB_; ++i) {
            o[4+i]  = y0 + (i*szy)/NB_;
            o[7+i]  = y0 + ((i+1)*szy + NB_-1)/NB_;
            o[10+i] = x0 + (i*szx)/NB_;
            o[13+i] = x0 + ((i+1)*szx + NB_-1)/NB_;
        }
    }
}

// grid (N_, F_/FPB); block 256 = 4 waves; wave: FPW features × RT-row tiles.
// Duplicate (clamped) rows in the last tile are exact copies -> max idempotent.
__global__ __launch_bounds__(256) void pool_kernel(
        const float* __restrict__ feat, const int* __restrict__ mask,
        const int* __restrict__ bb, float* __restrict__ out) {
    int n = blockIdx.x;
    int b = n >> 4;                      // / C_
    const int* o = bb + n * 16;
    int y0 = o[0], x0 = o[2];
    int bh = o[1] - y0, bw = o[3] - x0;  // each in [11,37]

    __shared__ float lmask[37 * 37];
    {
        const int* mbase = mask + (size_t)n * HW_ + (size_t)y0 * W_ + x0;
        int tot = bh * bw;
        for (int idx = threadIdx.x; idx < tot; idx += 256) {
            int dy = idx / bw, dx = idx - dy * bw;
            lmask[idx] = mbase[dy * W_ + dx] ? 1.0f : 0.0f;
        }
    }
    __syncthreads();

    int wave = threadIdx.x >> 6, lane = threadIdx.x & 63;
    int laneC = lane < bw ? lane : bw - 1;   // clamp -> loads always in-range
    int f0 = blockIdx.y * FPB + wave * FPW;
    const float* p = feat + (size_t)(b * F_ + f0) * HW_ + (size_t)y0 * W_ + x0 + laneC;

    int ys0 = o[4], ys1 = o[5], ys2 = o[6];
    int ye0 = o[7], ye1 = o[8], ye2 = o[9];

    float acc[3][FPW];
    #pragma unroll
    for (int i = 0; i < 3; ++i)
        #pragma unroll
        for (int k = 0; k < FPW; ++k) acc[i][k] = -FLT_MAX;

    int ntiles = (bh + RT - 1) / RT;
    int bhm1 = bh - 1;

    float cur[RT][FPW];
    #pragma unroll
    for (int r = 0; r < RT; ++r) {
        int dy = r < bhm1 ? r : bhm1;
        #pragma unroll
        for (int k = 0; k < FPW; ++k) cur[r][k] = p[k * HW_ + dy * W_];
    }

    for (int t = 0; t < ntiles; ++t) {
        int tn = (t + 1 < ntiles) ? t + 1 : t;
        float nxt[RT][FPW];
        #pragma unroll
        for (int r = 0; r < RT; ++r) {
            int dy = tn * RT + r; dy = dy < bhm1 ? dy : bhm1;
            #pragma unroll
            for (int k = 0; k < FPW; ++k) nxt[r][k] = p[k * HW_ + dy * W_];
        }
        #pragma unroll
        for (int r = 0; r < RT; ++r) {
            int dy = t * RT + r; dy = dy < bhm1 ? dy : bhm1;
            float mv = lmask[dy * bw + laneC];
            int y = y0 + dy;
            bool in0 = (y >= ys0) & (y < ye0);
            bool in1 = (y >= ys1) & (y < ye1);
            bool in2 = (y >= ys2) & (y < ye2);
            #pragma unroll
            for (int k = 0; k < FPW; ++k) {
                float v = mv * cur[r][k];
                if (in0) acc[0][k] = fmaxf(acc[0][k], v);
                if (in1) acc[1][k] = fmaxf(acc[1][k], v);
                if (in2) acc[2][k] = fmaxf(acc[2][k], v);
            }
        }
        #pragma unroll
        for (int r = 0; r < RT; ++r)
            #pragma unroll
            for (int k = 0; k < FPW; ++k) cur[r][k] = nxt[r][k];
    }

    // Epilogue: lanes >= bw hold garbage accs, but (x < xe <= x0+bw) masks them.
    int x = x0 + lane;
    int xs[3] = {o[10], o[11], o[12]};
    int xe[3] = {o[13], o[14], o[15]};

    #pragma unroll
    for (int k = 0; k < FPW; ++k) {
        float st = 0.0f;
        #pragma unroll
        for (int i = 0; i < 3; ++i) {
            #pragma unroll
            for (int j = 0; j < 3; ++j) {
                float val = (x >= xs[j] && x < xe[j]) ? acc[i][k] : -FLT_MAX;
                #pragma unroll
                for (int off = 32; off; off >>= 1)
                    val = fmaxf(val, __shfl_xor(val, off));
                st = (lane == i * 3 + j) ? val : st;
            }
        }
        if (lane < 9) out[(size_t)(n * F_ + f0 + k) * 9 + lane] = st;
    }
}

extern "C" void kernel_launch(void* const* d_in, const int* in_sizes, int n_in,
                              void* d_out, int out_size, void* d_ws, size_t ws_size,
                              hipStream_t stream) {
    const float* feat = (const float*)d_in[0];
    const int*   mask = (const int*)d_in[1];
    int* bb = (int*)d_ws;

    bbox_kernel<<<N_, 256, 0, stream>>>(mask, bb);
    dim3 grid(N_, F_ / FPB);
    pool_kernel<<<grid, 256, 0, stream>>>(feat, mask, bb, (float*)d_out);
}

// Round 4
// 184.776 us; speedup vs baseline: 1.3099x; 1.0324x over previous
//
#include <hip/hip_runtime.h>
#include <float.h>

#define B_  8
#define C_  16
#define N_  (B_*C_)
#define F_  256
#define H_  112
#define W_  112
#define HW_ (H_*W_)
#define NB_ 3

#define FPAR 2            // features processed in parallel in the row loop
#define FSEQ 2            // sequential feature pairs per wave
#define FPW  (FPAR*FSEQ)  // features per wave
#define WPB  4            // waves per block
#define FPB  (FPW*WPB)    // features per block = 16
#define LMS  64           // LDS mask row stride (floats)

// ws layout per cell (16 ints): y0,y1,x0,x1, ys[3], ye[3], xs[3], xe[3]

__global__ __launch_bounds__(256) void bbox_kernel(const int4* __restrict__ mask4,
                                                   int* __restrict__ bb) {
    int n = blockIdx.x, t = threadIdx.x;
    const int4* m = mask4 + (size_t)n * (HW_ / 4);
    int ymin = 1 << 20, ymax = -1, xmin = 1 << 20, xmax = -1;
    // W_/4 = 28 int4 per row; int4 never straddles rows.
    for (int i = t; i < HW_ / 4; i += 256) {
        int4 v = m[i];
        int y = i / 28;
        int xb = (i - y * 28) * 4;
        if (v.x | v.y | v.z | v.w) { ymin = min(ymin, y); ymax = max(ymax, y); }
        if (v.x) { xmin = min(xmin, xb);     xmax = max(xmax, xb);     }
        if (v.y) { xmin = min(xmin, xb + 1); xmax = max(xmax, xb + 1); }
        if (v.z) { xmin = min(xmin, xb + 2); xmax = max(xmax, xb + 2); }
        if (v.w) { xmin = min(xmin, xb + 3); xmax = max(xmax, xb + 3); }
    }
    #pragma unroll
    for (int off = 32; off; off >>= 1) {
        ymin = min(ymin, __shfl_xor(ymin, off));
        ymax = max(ymax, __shfl_xor(ymax, off));
        xmin = min(xmin, __shfl_xor(xmin, off));
        xmax = max(xmax, __shfl_xor(xmax, off));
    }
    __shared__ int red[4][4];
    int wave = t >> 6;
    if ((t & 63) == 0) {
        red[wave][0] = ymin; red[wave][1] = ymax;
        red[wave][2] = xmin; red[wave][3] = xmax;
    }
    __syncthreads();
    if (t == 0) {
        for (int w = 1; w < 4; ++w) {
            ymin = min(ymin, red[w][0]); ymax = max(ymax, red[w][1]);
            xmin = min(xmin, red[w][2]); xmax = max(xmax, red[w][3]);
        }
        int y0 = ymin, y1 = ymax + 1, x0 = xmin, x1 = xmax + 1;
        int* o = bb + n * 16;
        o[0] = y0; o[1] = y1; o[2] = x0; o[3] = x1;
        int szy = y1 - y0, szx = x1 - x0;
        for (int i = 0; i < NB_; ++i) {
            o[4+i]  = y0 + (i*szy)/NB_;
            o[7+i]  = y0 + ((i+1)*szy + NB_-1)/NB_;
            o[10+i] = x0 + (i*szx)/NB_;
            o[13+i] = x0 + ((i+1)*szx + NB_-1)/NB_;
        }
    }
}

// grid (N_, F_/FPB); block 256 = 4 waves.
// Lane map: xq = lane&15 -> float4 column group, rg = lane>>6..  rg = lane>>4 -> row within tile.
// Window aligned down to x0a = x0 & ~3; LDS mask padded to 64 floats/row (zeros outside [x0,x1)).
__global__ __launch_bounds__(256) void pool_kernel(
        const float* __restrict__ feat, const int* __restrict__ mask,
        const int* __restrict__ bb, float* __restrict__ out) {
    int n = blockIdx.x;
    int b = n >> 4;                       // / C_
    const int* o = bb + n * 16;
    int y0 = o[0], x0 = o[2];
    int bh = o[1] - y0, bw = o[3] - x0;   // each in [11,37]
    int x0a = x0 & ~3;
    int woff = x0 - x0a;
    int x1 = x0 + bw;

    __shared__ float lm[37 * LMS];        // 9.25 KB
    for (int idx = threadIdx.x; idx < bh * LMS; idx += 256) {
        int dy = idx >> 6, xo = idx & 63;
        int gx = x0a + xo;
        float v = 0.0f;
        if (gx >= x0 && gx < x1)
            v = mask[(size_t)n * HW_ + (size_t)(y0 + dy) * W_ + gx] ? 1.0f : 0.0f;
        lm[idx] = v;
    }
    __syncthreads();

    int lane = threadIdx.x & 63, wave = threadIdx.x >> 6;
    int xq = lane & 15, rg = lane >> 4;
    // clamp unused x-lanes onto column 0: no extra HBM fetch; their mask is 0.
    int xq4  = (4 * xq < woff + bw) ? 4 * xq : 0;
    int f0 = blockIdx.y * FPB + wave * FPW;

    int ys0 = o[4], ys1 = o[5], ys2 = o[6];
    int ye0 = o[7], ye1 = o[8], ye2 = o[9];
    int xs0 = o[10], xs1 = o[11], xs2 = o[12];
    int xe0 = o[13], xe1 = o[14], xe2 = o[15];

    int ntiles = (bh + 3) >> 2;
    int bhm1 = bh - 1;
    const float* gbase = feat + (size_t)(b * F_) * HW_ + (size_t)y0 * W_ + x0a + xq4;

    for (int fs = 0; fs < FSEQ; ++fs) {
        int f = f0 + fs * FPAR;
        const float* gp0 = gbase + (size_t)f * HW_;
        const float* gp1 = gp0 + HW_;

        float acc[3][4][FPAR];
        #pragma unroll
        for (int i = 0; i < 3; ++i)
            #pragma unroll
            for (int s = 0; s < 4; ++s)
                #pragma unroll
                for (int pp = 0; pp < FPAR; ++pp) acc[i][s][pp] = -FLT_MAX;

        int dy0 = min(rg, bhm1);
        float4 cur0 = *(const float4*)(gp0 + dy0 * W_);
        float4 cur1 = *(const float4*)(gp1 + dy0 * W_);

        for (int t = 0; t < ntiles; ++t) {
            int tn = (t + 1 < ntiles) ? t + 1 : t;
            int dyn = min(4 * tn + rg, bhm1);
            float4 nxt0 = *(const float4*)(gp0 + dyn * W_);
            float4 nxt1 = *(const float4*)(gp1 + dyn * W_);

            int dyc = min(4 * t + rg, bhm1);
            float4 mv = *(const float4*)(&lm[dyc * LMS + 4 * xq]);
            int y = y0 + dyc;
            bool in0 = (y >= ys0) & (y < ye0);
            bool in1 = (y >= ys1) & (y < ye1);
            bool in2 = (y >= ys2) & (y < ye2);

            float v0[4] = {mv.x * cur0.x, mv.y * cur0.y, mv.z * cur0.z, mv.w * cur0.w};
            float v1[4] = {mv.x * cur1.x, mv.y * cur1.y, mv.z * cur1.z, mv.w * cur1.w};
            #pragma unroll
            for (int s = 0; s < 4; ++s) {
                if (in0) { acc[0][s][0] = fmaxf(acc[0][s][0], v0[s]);
                           acc[0][s][1] = fmaxf(acc[0][s][1], v1[s]); }
                if (in1) { acc[1][s][0] = fmaxf(acc[1][s][0], v0[s]);
                           acc[1][s][1] = fmaxf(acc[1][s][1], v1[s]); }
                if (in2) { acc[2][s][0] = fmaxf(acc[2][s][0], v0[s]);
                           acc[2][s][1] = fmaxf(acc[2][s][1], v1[s]); }
            }
            cur0 = nxt0; cur1 = nxt1;
        }

        // Epilogue: fold slots into x-bins per lane, then 64-lane butterfly max.
        int xg = x0a + 4 * xq;
        #pragma unroll
        for (int pp = 0; pp < FPAR; ++pp) {
            float part[9];
            #pragma unroll
            for (int i = 0; i < 3; ++i) {
                #pragma unroll
                for (int s = 0; s < 4; ++s) {
                    int xx = xg + s;
                    float a = acc[i][s][pp];
                    float p0 = (xx >= xs0 && xx < xe0) ? a : -FLT_MAX;
                    float p1 = (xx >= xs1 && xx < xe1) ? a : -FLT_MAX;
                    float p2 = (xx >= xs2 && xx < xe2) ? a : -FLT_MAX;
                    if (s == 0) { part[i*3+0] = p0; part[i*3+1] = p1; part[i*3+2] = p2; }
                    else {
                        part[i*3+0] = fmaxf(part[i*3+0], p0);
                        part[i*3+1] = fmaxf(part[i*3+1], p1);
                        part[i*3+2] = fmaxf(part[i*3+2], p2);
                    }
                }
            }
            #pragma unroll
            for (int off = 32; off; off >>= 1)
                #pragma unroll
                for (int q = 0; q < 9; ++q)
                    part[q] = fmaxf(part[q], __shfl_xor(part[q], off));
            float st = part[0];
            #pragma unroll
            for (int q = 1; q < 9; ++q) st = (lane == q) ? part[q] : st;
            if (lane < 9)
                out[(size_t)(n * F_ + f + pp) * 9 + lane] = st;
        }
    }
}

extern "C" void kernel_launch(void* const* d_in, const int* in_sizes, int n_in,
                              void* d_out, int out_size, void* d_ws, size_t ws_size,
                              hipStream_t stream) {
    const float* feat = (const float*)d_in[0];
    const int*   mask = (const int*)d_in[1];
    int* bb = (int*)d_ws;

    bbox_kernel<<<N_, 256, 0, stream>>>((const int4*)mask, bb);
    dim3 grid(N_, F_ / FPB);
    pool_kernel<<<grid, 256, 0, stream>>>(feat, mask, bb, (float*)d_out);
}